// Round 10
// baseline (421.782 us; speedup 1.0000x reference)
//
#include <hip/hip_runtime.h>
#include <hip/hip_bf16.h>
#include <stdint.h>

#define D_ 1024
#define H_ 16
#define DH_ 64
#define S_ 2048
#define B_ 16
static constexpr float SCALE = 0.125f;  // 1/sqrt(64)

typedef __bf16 bf16_t;
typedef __bf16 bf16x8 __attribute__((ext_vector_type(8)));
typedef __bf16 bf16x4 __attribute__((ext_vector_type(4)));
typedef float  f32x4  __attribute__((ext_vector_type(4)));

__device__ __forceinline__ void llds16(const void* g, void* l) {
  __builtin_amdgcn_global_load_lds(
      (const __attribute__((address_space(1))) void*)g,
      (__attribute__((address_space(3))) void*)l, 16, 0, 0);
}

// ---------------------------------------------------------------------------
// 3x 1024x1024 f32 -> bf16 transpose in one launch: dst[n][k] = src[k][n]
// ---------------------------------------------------------------------------
__global__ __launch_bounds__(256)
void transpose1024_all(const float* __restrict__ s0, const float* __restrict__ s1,
                       const float* __restrict__ s2, bf16_t* __restrict__ d0,
                       bf16_t* __restrict__ d1, bf16_t* __restrict__ d2) {
  __shared__ bf16_t t[64][65];
  const float* src = (blockIdx.z == 0) ? s0 : (blockIdx.z == 1) ? s1 : s2;
  bf16_t* dst      = (blockIdx.z == 0) ? d0 : (blockIdx.z == 1) ? d1 : d2;
  const int n0 = blockIdx.x * 64, k0 = blockIdx.y * 64;
  const int r = threadIdx.x >> 4, c4 = (threadIdx.x & 15) * 4;
#pragma unroll
  for (int p = 0; p < 4; ++p) {
    int row = p * 16 + r;
    f32x4 f = *(const f32x4*)&src[(size_t)(k0 + row) * 1024 + n0 + c4];
#pragma unroll
    for (int i = 0; i < 4; ++i) t[row][c4 + i] = (bf16_t)f[i];
  }
  __syncthreads();
#pragma unroll
  for (int p = 0; p < 4; ++p) {
    int row = p * 16 + r;
    bf16x4 v;
#pragma unroll
    for (int i = 0; i < 4; ++i) v[i] = t[c4 + i][row];
    *(bf16x4*)&dst[(size_t)(n0 + row) * 1024 + k0 + c4] = v;
  }
}

// [1024][16] f32 -> [16][1024] bf16, both Wqa and Wka in one launch
__global__ __launch_bounds__(256)
void transpose_small_all(const float* __restrict__ sa, const float* __restrict__ sb,
                         bf16_t* __restrict__ da, bf16_t* __restrict__ db) {
  int g = blockIdx.x * 256 + threadIdx.x;
  const float* src = (g < 1024) ? sa : sb;
  bf16_t* dst      = (g < 1024) ? da : db;
  int k = g & 1023;
#pragma unroll
  for (int h = 0; h < H_; ++h) dst[h * 1024 + k] = (bf16_t)src[k * H_ + h];
}

// ---------------------------------------------------------------------------
// GEMM: C[M][1024] = A[M][1024] @ BT[1024][1024]^T + bias (+epilogue)
// m97 128x128 structure + slot-rotation LDS swizzle (0 conflicts, r8-measured)
// + LDS-staged coalesced epilogue. launch_bounds (256,2): r9's (256,4) gave
// no occupancy gain (37->38%) but cost ILP (gemm 124->149) — reverted.
// MODE 0: A = f32 hs (reg-staged cvt)             -> bf16 (mixed_q)
// MODE 1: A = f32 hs, *pscale[b][col]             -> bf16 (mixed_qk)
// MODE 2: A = bf16 mq * pkA[b][k] (fused), +resid -> f32 (final output)
// ---------------------------------------------------------------------------
template <int MODE>
__global__ __launch_bounds__(256, 2)
void gemm_bt(const void* __restrict__ Asrc, const bf16_t* __restrict__ BT,
             const float* __restrict__ bias, void* __restrict__ Cout,
             const float* __restrict__ pscale, const bf16_t* __restrict__ resid,
             const float* __restrict__ pkA) {
  constexpr int K = 1024, N = 1024;
  __shared__ __align__(16) bf16_t lA[128 * 32];
  __shared__ __align__(16) bf16_t lB[128 * 32];
  __shared__ __align__(16) float est[4][16 * 68];
  const int tid = threadIdx.x;
  const int lane = tid & 63, wid = tid >> 6;
  const int wr = wid >> 1, wc = wid & 1;

  // XCD swizzle: nwg=2048, 2048%8==0
  const int wgid = (blockIdx.x & 7) * 256 + (blockIdx.x >> 3);
  const int m0 = (wgid >> 3) * 128;
  const int n0 = (wgid & 7) * 128;
  const int b = m0 / S_;

  const int ar = lane & 15;
  const int kq = lane >> 4;   // k-chunk 0..3 within the 32-k tile

  // staging chunk map (2 chunks per thread per matrix); lds row r slot s
  // holds global k-chunk (s - (r>>1)) & 3  (involution rotation swizzle)
  int rowc[2], colc[2], dstoff[2];
#pragma unroll
  for (int j = 0; j < 2; ++j) {
    int c = j * 256 + tid;          // 0..511
    int row = c >> 2, s = c & 3;
    rowc[j] = row;
    colc[j] = (((s - (row >> 1)) & 3) << 3);
    dstoff[j] = c * 8;
  }

  f32x4 acc[4][4] = {};

  for (int k0 = 0; k0 < K; k0 += 32) {
#pragma unroll
    for (int j = 0; j < 2; ++j) {
      const bf16_t* gb = BT + (size_t)(n0 + rowc[j]) * K + k0 + colc[j];
      llds16(gb, lB + dstoff[j]);
      if (MODE == 2) {
        // fused weighted: A-chunk = mq * pk[b][k]
        const bf16_t* Ab = (const bf16_t*)Asrc;
        bf16x8 v = *(const bf16x8*)(Ab + (size_t)(m0 + rowc[j]) * K + k0 + colc[j]);
        const float* pkp = pkA + b * D_ + k0 + colc[j];
        f32x4 p0 = *(const f32x4*)pkp;
        f32x4 p1 = *(const f32x4*)(pkp + 4);
        bf16x8 o;
#pragma unroll
        for (int i = 0; i < 4; ++i) {
          o[i]     = (bf16_t)((float)v[i] * p0[i]);
          o[4 + i] = (bf16_t)((float)v[4 + i] * p1[i]);
        }
        *(bf16x8*)&lA[dstoff[j]] = o;
      } else {
        // A is f32 hidden_states: reg-staged load + convert (no separate pass)
        const float* Af = (const float*)Asrc;
        const float* ga = Af + (size_t)(m0 + rowc[j]) * K + k0 + colc[j];
        f32x4 a0 = *(const f32x4*)ga;
        f32x4 a1 = *(const f32x4*)(ga + 4);
        bf16x8 o;
#pragma unroll
        for (int i = 0; i < 4; ++i) { o[i] = (bf16_t)a0[i]; o[4 + i] = (bf16_t)a1[i]; }
        *(bf16x8*)&lA[dstoff[j]] = o;
      }
    }
    __syncthreads();
    bf16x8 af[4], bg[4];
#pragma unroll
    for (int m = 0; m < 4; ++m) {
      int r = wr * 64 + m * 16 + ar;
      af[m] = *(const bf16x8*)&lA[r * 32 + (((kq + (r >> 1)) & 3) << 3)];
    }
#pragma unroll
    for (int n = 0; n < 4; ++n) {
      int r = wc * 64 + n * 16 + ar;
      bg[n] = *(const bf16x8*)&lB[r * 32 + (((kq + (r >> 1)) & 3) << 3)];
    }
#pragma unroll
    for (int m = 0; m < 4; ++m)
#pragma unroll
      for (int n = 0; n < 4; ++n)
        acc[m][n] = __builtin_amdgcn_mfma_f32_16x16x32_bf16(af[m], bg[n], acc[m][n], 0, 0, 0);
    __syncthreads();
  }

  // ----- epilogue: LDS-staged coalesced stores (refcheck'd r5-r9) -----
  float* st = est[wid];
  const int erow = lane >> 2;          // 0..15
  const int ecol = (lane & 3) * 16;    // 0,16,32,48
  const int gcb = n0 + wc * 64;        // wave col base
  const int qrow = (lane >> 4) * 4;
  const int qcol = lane & 15;
  f32x4 bb[4], ps[4];
#pragma unroll
  for (int q = 0; q < 4; ++q) bb[q] = *(const f32x4*)&bias[gcb + ecol + q * 4];
  if (MODE == 1) {
#pragma unroll
    for (int q = 0; q < 4; ++q) ps[q] = *(const f32x4*)&pscale[b * D_ + gcb + ecol + q * 4];
  }
#pragma unroll
  for (int m = 0; m < 4; ++m) {
#pragma unroll
    for (int n = 0; n < 4; ++n)
#pragma unroll
      for (int j = 0; j < 4; ++j)
        st[(qrow + j) * 68 + n * 16 + qcol] = acc[m][n][j];
    asm volatile("s_waitcnt lgkmcnt(0)" ::: "memory");
    __builtin_amdgcn_sched_barrier(0);
    const int grow = m0 + wr * 64 + m * 16 + erow;
    f32x4 v[4];
#pragma unroll
    for (int q = 0; q < 4; ++q) v[q] = *(f32x4*)&st[erow * 68 + ecol + q * 4];
#pragma unroll
    for (int q = 0; q < 4; ++q)
#pragma unroll
      for (int i = 0; i < 4; ++i) v[q][i] += bb[q][i];
    if (MODE == 1) {
#pragma unroll
      for (int q = 0; q < 4; ++q)
#pragma unroll
        for (int i = 0; i < 4; ++i) v[q][i] *= ps[q][i];
    }
    if (MODE == 2) {
      bf16x8 r0 = *(const bf16x8*)&resid[(size_t)grow * N + gcb + ecol];
      bf16x8 r1 = *(const bf16x8*)&resid[(size_t)grow * N + gcb + ecol + 8];
#pragma unroll
      for (int i = 0; i < 4; ++i) { v[0][i] += (float)r0[i]; v[1][i] += (float)r0[4 + i]; }
#pragma unroll
      for (int i = 0; i < 4; ++i) { v[2][i] += (float)r1[i]; v[3][i] += (float)r1[4 + i]; }
      float* op = (float*)Cout + (size_t)grow * N + gcb + ecol;
#pragma unroll
      for (int q = 0; q < 4; ++q) *(f32x4*)&op[q * 4] = v[q];
    } else {
      bf16x8 o0, o1;
#pragma unroll
      for (int i = 0; i < 4; ++i) { o0[i] = (bf16_t)v[0][i]; o0[4 + i] = (bf16_t)v[1][i]; }
#pragma unroll
      for (int i = 0; i < 4; ++i) { o1[i] = (bf16_t)v[2][i]; o1[4 + i] = (bf16_t)v[3][i]; }
      bf16_t* op = (bf16_t*)Cout + (size_t)grow * N + gcb + ecol;
      *(bf16x8*)&op[0] = o0;
      *(bf16x8*)&op[8] = o1;
    }
  }
}

// ---------------------------------------------------------------------------
// scores[b*H+h][s] = (X[b,s,:] . WaT[h,:] + ba[h]) * SCALE + mask[b][s]
// ba, mask read as f32 directly.
// ---------------------------------------------------------------------------
__global__ __launch_bounds__(256)
void score_kernel(const bf16_t* __restrict__ X, const bf16_t* __restrict__ WaT,
                  const float* __restrict__ ba, const float* __restrict__ mask,
                  float* __restrict__ scores) {
  const int lane = threadIdx.x & 63, wid = threadIdx.x >> 6;
  const int m0 = blockIdx.x * 64 + wid * 16;
  const int ar = lane & 15, ak = (lane >> 4) * 8;
  f32x4 acc = {};
  for (int k0 = 0; k0 < D_; k0 += 32) {
    bf16x8 a = *(const bf16x8*)&X[(size_t)(m0 + ar) * D_ + k0 + ak];
    bf16x8 b = *(const bf16x8*)&WaT[(size_t)ar * D_ + k0 + ak];
    acc = __builtin_amdgcn_mfma_f32_16x16x32_bf16(a, b, acc, 0, 0, 0);
  }
  const int h = lane & 15;
  const int srow = m0 + (lane >> 4) * 4;
  const int bb = srow / S_;
  const int s0 = srow - bb * S_;
  const float bah = ba[h];
  f32x4 mv = *(const f32x4*)&mask[(size_t)bb * S_ + s0];
  f32x4 outv;
#pragma unroll
  for (int j = 0; j < 4; ++j)
    outv[j] = (acc[j] + bah) * SCALE + mv[j];
  *(f32x4*)&scores[((size_t)(bb * H_ + h)) * S_ + s0] = outv;
}

// ---------------------------------------------------------------------------
// softmax over each scores row -> normalized weights
// ---------------------------------------------------------------------------
__global__ __launch_bounds__(256)
void softmax_rows(const float* __restrict__ scores, float* __restrict__ wout) {
  __shared__ float rA[4], rB[4];
  const int tid = threadIdx.x, lane = tid & 63, wid = tid >> 6;
  const float* srow = scores + (size_t)blockIdx.x * S_;
  float* wrow = wout + (size_t)blockIdx.x * S_;
  f32x4 v0 = *(const f32x4*)&srow[tid * 4];
  f32x4 v1 = *(const f32x4*)&srow[1024 + tid * 4];
  float mx = fmaxf(fmaxf(fmaxf(v0[0], v0[1]), fmaxf(v0[2], v0[3])),
                   fmaxf(fmaxf(v1[0], v1[1]), fmaxf(v1[2], v1[3])));
#pragma unroll
  for (int o = 32; o; o >>= 1) mx = fmaxf(mx, __shfl_xor(mx, o));
  if (lane == 0) rA[wid] = mx;
  __syncthreads();
  mx = fmaxf(fmaxf(rA[0], rA[1]), fmaxf(rA[2], rA[3]));
  float sum = 0.f;
#pragma unroll
  for (int i = 0; i < 4; ++i) { v0[i] = __expf(v0[i] - mx); sum += v0[i]; }
#pragma unroll
  for (int i = 0; i < 4; ++i) { v1[i] = __expf(v1[i] - mx); sum += v1[i]; }
#pragma unroll
  for (int o = 32; o; o >>= 1) sum += __shfl_xor(sum, o);
  if (lane == 0) rB[wid] = sum;
  __syncthreads();
  sum = rB[0] + rB[1] + rB[2] + rB[3];
  const float inv = 1.0f / sum;
#pragma unroll
  for (int i = 0; i < 4; ++i) { v0[i] *= inv; v1[i] *= inv; }
  *(f32x4*)&wrow[tid * 4] = v0;
  *(f32x4*)&wrow[1024 + tid * 4] = v1;
}

// ---------------------------------------------------------------------------
// pool partials over 32-row chunks (coalesced bf16x8)
// ---------------------------------------------------------------------------
__global__ __launch_bounds__(256)
void pool_partial(const bf16_t* __restrict__ X, const float* __restrict__ w,
                  float* __restrict__ partials) {
  __shared__ float sm[2][1024];
  const int tid = threadIdx.x;
  const int chunk = blockIdx.x, b = blockIdx.y;
  const int s0 = chunk * 32;
  const int dc = (tid & 127) * 8;
  const int sp = tid >> 7;
  const int h = dc >> 6;
  const float* wrow = w + ((size_t)b * H_ + h) * S_ + s0;
  const bf16_t* Xb = X + ((size_t)b * S_ + s0) * D_ + dc;
  float acc[8] = {};
  for (int s = sp; s < 32; s += 2) {
    bf16x8 xv = *(const bf16x8*)&Xb[(size_t)s * D_];
    float wt = wrow[s];
#pragma unroll
    for (int j = 0; j < 8; ++j) acc[j] += wt * (float)xv[j];
  }
#pragma unroll
  for (int j = 0; j < 8; ++j) sm[sp][dc + j] = acc[j];
  __syncthreads();
  const int d0 = tid * 4;
  f32x4 r;
#pragma unroll
  for (int j = 0; j < 4; ++j) r[j] = sm[0][d0 + j] + sm[1][d0 + j];
  *(f32x4*)&partials[((size_t)chunk * B_ + b) * D_ + d0] = r;
}

__global__ __launch_bounds__(256)
void pool_reduce(const float* __restrict__ partials, float* __restrict__ pooled) {
  const int idx = blockIdx.x * 256 + threadIdx.x;
  float s = 0.f;
#pragma unroll 8
  for (int c = 0; c < 64; ++c) s += partials[(size_t)c * (B_ * D_) + idx];
  pooled[idx] = s;
}

// ---------------------------------------------------------------------------
extern "C" void kernel_launch(void* const* d_in, const int* in_sizes, int n_in,
                              void* d_out, int out_size, void* d_ws, size_t ws_size,
                              hipStream_t stream) {
  const float* hs   = (const float*)d_in[0];
  const float* mask = (const float*)d_in[1];
  const float* Wq   = (const float*)d_in[2];
  const float* bq   = (const float*)d_in[3];
  const float* Wqa  = (const float*)d_in[4];
  const float* bqa  = (const float*)d_in[5];
  const float* Wk   = (const float*)d_in[6];
  const float* bk   = (const float*)d_in[7];
  const float* Wka  = (const float*)d_in[8];
  const float* bka  = (const float*)d_in[9];
  const float* Wt   = (const float*)d_in[10];
  const float* bt   = (const float*)d_in[11];

  char* ws = (char*)d_ws;
  float*  pq    = (float*)(ws + (64u << 10));
  float*  pk    = (float*)(ws + (128u << 10));
  bf16_t* WqaT  = (bf16_t*)(ws + (1u << 20));
  bf16_t* WkaT  = (bf16_t*)(ws + (1u << 20) + 32768);
  bf16_t* WqT   = (bf16_t*)(ws + (2u << 20));
  bf16_t* WkT   = (bf16_t*)(ws + (4u << 20));
  bf16_t* WtT   = (bf16_t*)(ws + (6u << 20));
  bf16_t* mq    = (bf16_t*)(ws + (8u << 20));
  bf16_t* mqk   = (bf16_t*)(ws + (8u << 20) + ((size_t)64 << 20));
  float* scores = (float*)(ws + (8u << 20) + ((size_t)128 << 20));
  float* wsm    = (float*)(ws + (8u << 20) + ((size_t)130 << 20));
  float* parts  = (float*)(ws + (8u << 20) + ((size_t)132 << 20));

  // prep: weight transposes only
  transpose1024_all<<<dim3(16, 16, 3), 256, 0, stream>>>(Wq, Wk, Wt, WqT, WkT, WtT);
  transpose_small_all<<<8, 256, 0, stream>>>(Wqa, Wka, WqaT, WkaT);

  // mixed_q = hs @ Wq + bq   (f32 A, fused convert)
  gemm_bt<0><<<2048, 256, 0, stream>>>(hs, WqT, bq, mq, nullptr, nullptr, nullptr);

  score_kernel<<<512, 256, 0, stream>>>(mq, WqaT, bqa, mask, scores);
  softmax_rows<<<256, 256, 0, stream>>>(scores, wsm);
  pool_partial<<<dim3(64, 16), 256, 0, stream>>>(mq, wsm, parts);
  pool_reduce<<<64, 256, 0, stream>>>(parts, pq);

  // mixed_qk = (hs @ Wk + bk) * pooled_q   (f32 A, fused convert)
  gemm_bt<1><<<2048, 256, 0, stream>>>(hs, WkT, bk, mqk, pq, nullptr, nullptr);

  score_kernel<<<512, 256, 0, stream>>>(mqk, WkaT, bka, mask, scores);
  softmax_rows<<<256, 256, 0, stream>>>(scores, wsm);
  pool_partial<<<dim3(64, 16), 256, 0, stream>>>(mqk, wsm, parts);
  pool_reduce<<<64, 256, 0, stream>>>(parts, pk);

  // out = (mq * pk) @ Wt + bt + mixed_q   (weighted fused into A-staging)
  gemm_bt<2><<<2048, 256, 0, stream>>>(mq, WtT, bt, d_out, nullptr, mq, pk);
}

// Round 11
// 398.629 us; speedup vs baseline: 1.0581x; 1.0581x over previous
//
#include <hip/hip_runtime.h>
#include <hip/hip_bf16.h>
#include <stdint.h>

#define D_ 1024
#define H_ 16
#define DH_ 64
#define S_ 2048
#define B_ 16
static constexpr float SCALE = 0.125f;  // 1/sqrt(64)

typedef __bf16 bf16_t;
typedef __bf16 bf16x8 __attribute__((ext_vector_type(8)));
typedef __bf16 bf16x4 __attribute__((ext_vector_type(4)));
typedef float  f32x4  __attribute__((ext_vector_type(4)));

__device__ __forceinline__ void llds16(const void* g, void* l) {
  __builtin_amdgcn_global_load_lds(
      (const __attribute__((address_space(1))) void*)g,
      (__attribute__((address_space(3))) void*)l, 16, 0, 0);
}

// ---------------------------------------------------------------------------
// hidden_states f32 -> bf16 (one pass; both big GEMMs then stage bf16 A via
// global_load_lds — r8-measured 124.5us/GEMM vs 149 for f32 reg-staged A)
// ---------------------------------------------------------------------------
__global__ __launch_bounds__(256)
void f32_to_bf16(const float* __restrict__ src, bf16_t* __restrict__ dst) {
  size_t base = ((size_t)blockIdx.x * 256 + threadIdx.x) * 8;
  f32x4 a = *(const f32x4*)&src[base];
  f32x4 b = *(const f32x4*)&src[base + 4];
  bf16x8 o;
#pragma unroll
  for (int i = 0; i < 4; ++i) { o[i] = (bf16_t)a[i]; o[4 + i] = (bf16_t)b[i]; }
  *(bf16x8*)&dst[base] = o;
}

// ---------------------------------------------------------------------------
// 3x 1024x1024 f32 -> bf16 transpose in one launch: dst[n][k] = src[k][n]
// ---------------------------------------------------------------------------
__global__ __launch_bounds__(256)
void transpose1024_all(const float* __restrict__ s0, const float* __restrict__ s1,
                       const float* __restrict__ s2, bf16_t* __restrict__ d0,
                       bf16_t* __restrict__ d1, bf16_t* __restrict__ d2) {
  __shared__ bf16_t t[64][65];
  const float* src = (blockIdx.z == 0) ? s0 : (blockIdx.z == 1) ? s1 : s2;
  bf16_t* dst      = (blockIdx.z == 0) ? d0 : (blockIdx.z == 1) ? d1 : d2;
  const int n0 = blockIdx.x * 64, k0 = blockIdx.y * 64;
  const int r = threadIdx.x >> 4, c4 = (threadIdx.x & 15) * 4;
#pragma unroll
  for (int p = 0; p < 4; ++p) {
    int row = p * 16 + r;
    f32x4 f = *(const f32x4*)&src[(size_t)(k0 + row) * 1024 + n0 + c4];
#pragma unroll
    for (int i = 0; i < 4; ++i) t[row][c4 + i] = (bf16_t)f[i];
  }
  __syncthreads();
#pragma unroll
  for (int p = 0; p < 4; ++p) {
    int row = p * 16 + r;
    bf16x4 v;
#pragma unroll
    for (int i = 0; i < 4; ++i) v[i] = t[c4 + i][row];
    *(bf16x4*)&dst[(size_t)(n0 + row) * 1024 + k0 + c4] = v;
  }
}

// [1024][16] f32 -> [16][1024] bf16, both Wqa and Wka in one launch
__global__ __launch_bounds__(256)
void transpose_small_all(const float* __restrict__ sa, const float* __restrict__ sb,
                         bf16_t* __restrict__ da, bf16_t* __restrict__ db) {
  int g = blockIdx.x * 256 + threadIdx.x;
  const float* src = (g < 1024) ? sa : sb;
  bf16_t* dst      = (g < 1024) ? da : db;
  int k = g & 1023;
#pragma unroll
  for (int h = 0; h < H_; ++h) dst[h * 1024 + k] = (bf16_t)src[k * H_ + h];
}

// ---------------------------------------------------------------------------
// GEMM: C[M][1024] = A[M][1024] @ BT[1024][1024]^T + bias (+epilogue)
// r8-measured-best config: m97 128x128 structure, global_load_lds(16B) A/B
// staging for MODE0/1, slot-rotation LDS swizzle (0 conflicts), LDS-staged
// coalesced epilogue, launch_bounds (256,2).
// MODE 0: A = bf16 hsb                             -> bf16 (mixed_q)
// MODE 1: A = bf16 hsb, *pscale[b][col]            -> bf16 (mixed_qk)
// MODE 2: A = bf16 mq * pkA[b][k] (fused), +resid  -> f32 (final output)
// ---------------------------------------------------------------------------
template <int MODE>
__global__ __launch_bounds__(256, 2)
void gemm_bt(const bf16_t* __restrict__ A, const bf16_t* __restrict__ BT,
             const float* __restrict__ bias, void* __restrict__ Cout,
             const float* __restrict__ pscale, const bf16_t* __restrict__ resid,
             const float* __restrict__ pkA) {
  constexpr int K = 1024, N = 1024;
  __shared__ __align__(16) bf16_t lA[128 * 32];
  __shared__ __align__(16) bf16_t lB[128 * 32];
  __shared__ __align__(16) float est[4][16 * 68];
  const int tid = threadIdx.x;
  const int lane = tid & 63, wid = tid >> 6;
  const int wr = wid >> 1, wc = wid & 1;

  // XCD swizzle: nwg=2048, 2048%8==0
  const int wgid = (blockIdx.x & 7) * 256 + (blockIdx.x >> 3);
  const int m0 = (wgid >> 3) * 128;
  const int n0 = (wgid & 7) * 128;
  const int b = m0 / S_;

  const int ar = lane & 15;
  const int kq = lane >> 4;   // k-chunk 0..3 within the 32-k tile

  // staging chunk map (2 chunks per thread per matrix); lds row r slot s
  // holds global k-chunk (s - (r>>1)) & 3  (involution rotation swizzle)
  int rowc[2], colc[2], dstoff[2];
#pragma unroll
  for (int j = 0; j < 2; ++j) {
    int c = j * 256 + tid;          // 0..511
    int row = c >> 2, s = c & 3;
    rowc[j] = row;
    colc[j] = (((s - (row >> 1)) & 3) << 3);
    dstoff[j] = c * 8;
  }

  f32x4 acc[4][4] = {};

  for (int k0 = 0; k0 < K; k0 += 32) {
#pragma unroll
    for (int j = 0; j < 2; ++j) {
      const bf16_t* gb = BT + (size_t)(n0 + rowc[j]) * K + k0 + colc[j];
      llds16(gb, lB + dstoff[j]);
      if (MODE == 2) {
        // fused weighted: A-chunk = mq * pk[b][k], reg-staged
        bf16x8 v = *(const bf16x8*)(A + (size_t)(m0 + rowc[j]) * K + k0 + colc[j]);
        const float* pkp = pkA + b * D_ + k0 + colc[j];
        f32x4 p0 = *(const f32x4*)pkp;
        f32x4 p1 = *(const f32x4*)(pkp + 4);
        bf16x8 o;
#pragma unroll
        for (int i = 0; i < 4; ++i) {
          o[i]     = (bf16_t)((float)v[i] * p0[i]);
          o[4 + i] = (bf16_t)((float)v[4 + i] * p1[i]);
        }
        *(bf16x8*)&lA[dstoff[j]] = o;
      } else {
        const bf16_t* ga = A + (size_t)(m0 + rowc[j]) * K + k0 + colc[j];
        llds16(ga, lA + dstoff[j]);
      }
    }
    __syncthreads();
    bf16x8 af[4], bg[4];
#pragma unroll
    for (int m = 0; m < 4; ++m) {
      int r = wr * 64 + m * 16 + ar;
      af[m] = *(const bf16x8*)&lA[r * 32 + (((kq + (r >> 1)) & 3) << 3)];
    }
#pragma unroll
    for (int n = 0; n < 4; ++n) {
      int r = wc * 64 + n * 16 + ar;
      bg[n] = *(const bf16x8*)&lB[r * 32 + (((kq + (r >> 1)) & 3) << 3)];
    }
#pragma unroll
    for (int m = 0; m < 4; ++m)
#pragma unroll
      for (int n = 0; n < 4; ++n)
        acc[m][n] = __builtin_amdgcn_mfma_f32_16x16x32_bf16(af[m], bg[n], acc[m][n], 0, 0, 0);
    __syncthreads();
  }

  // ----- epilogue: LDS-staged coalesced stores (refcheck'd r5-r10) -----
  float* st = est[wid];
  const int erow = lane >> 2;          // 0..15
  const int ecol = (lane & 3) * 16;    // 0,16,32,48
  const int gcb = n0 + wc * 64;        // wave col base
  const int qrow = (lane >> 4) * 4;
  const int qcol = lane & 15;
  f32x4 bb[4], ps[4];
#pragma unroll
  for (int q = 0; q < 4; ++q) bb[q] = *(const f32x4*)&bias[gcb + ecol + q * 4];
  if (MODE == 1) {
#pragma unroll
    for (int q = 0; q < 4; ++q) ps[q] = *(const f32x4*)&pscale[b * D_ + gcb + ecol + q * 4];
  }
#pragma unroll
  for (int m = 0; m < 4; ++m) {
#pragma unroll
    for (int n = 0; n < 4; ++n)
#pragma unroll
      for (int j = 0; j < 4; ++j)
        st[(qrow + j) * 68 + n * 16 + qcol] = acc[m][n][j];
    asm volatile("s_waitcnt lgkmcnt(0)" ::: "memory");
    __builtin_amdgcn_sched_barrier(0);
    const int grow = m0 + wr * 64 + m * 16 + erow;
    f32x4 v[4];
#pragma unroll
    for (int q = 0; q < 4; ++q) v[q] = *(f32x4*)&st[erow * 68 + ecol + q * 4];
#pragma unroll
    for (int q = 0; q < 4; ++q)
#pragma unroll
      for (int i = 0; i < 4; ++i) v[q][i] += bb[q][i];
    if (MODE == 1) {
#pragma unroll
      for (int q = 0; q < 4; ++q)
#pragma unroll
        for (int i = 0; i < 4; ++i) v[q][i] *= ps[q][i];
    }
    if (MODE == 2) {
      bf16x8 r0 = *(const bf16x8*)&resid[(size_t)grow * N + gcb + ecol];
      bf16x8 r1 = *(const bf16x8*)&resid[(size_t)grow * N + gcb + ecol + 8];
#pragma unroll
      for (int i = 0; i < 4; ++i) { v[0][i] += (float)r0[i]; v[1][i] += (float)r0[4 + i]; }
#pragma unroll
      for (int i = 0; i < 4; ++i) { v[2][i] += (float)r1[i]; v[3][i] += (float)r1[4 + i]; }
      float* op = (float*)Cout + (size_t)grow * N + gcb + ecol;
#pragma unroll
      for (int q = 0; q < 4; ++q) *(f32x4*)&op[q * 4] = v[q];
    } else {
      bf16x8 o0, o1;
#pragma unroll
      for (int i = 0; i < 4; ++i) { o0[i] = (bf16_t)v[0][i]; o0[4 + i] = (bf16_t)v[1][i]; }
#pragma unroll
      for (int i = 0; i < 4; ++i) { o1[i] = (bf16_t)v[2][i]; o1[4 + i] = (bf16_t)v[3][i]; }
      bf16_t* op = (bf16_t*)Cout + (size_t)grow * N + gcb + ecol;
      *(bf16x8*)&op[0] = o0;
      *(bf16x8*)&op[8] = o1;
    }
  }
}

// ---------------------------------------------------------------------------
// scores[b*H+h][s] = (X[b,s,:] . WaT[h,:] + ba[h]) * SCALE + mask[b][s]
// ba, mask read as f32 directly.
// ---------------------------------------------------------------------------
__global__ __launch_bounds__(256)
void score_kernel(const bf16_t* __restrict__ X, const bf16_t* __restrict__ WaT,
                  const float* __restrict__ ba, const float* __restrict__ mask,
                  float* __restrict__ scores) {
  const int lane = threadIdx.x & 63, wid = threadIdx.x >> 6;
  const int m0 = blockIdx.x * 64 + wid * 16;
  const int ar = lane & 15, ak = (lane >> 4) * 8;
  f32x4 acc = {};
  for (int k0 = 0; k0 < D_; k0 += 32) {
    bf16x8 a = *(const bf16x8*)&X[(size_t)(m0 + ar) * D_ + k0 + ak];
    bf16x8 b = *(const bf16x8*)&WaT[(size_t)ar * D_ + k0 + ak];
    acc = __builtin_amdgcn_mfma_f32_16x16x32_bf16(a, b, acc, 0, 0, 0);
  }
  const int h = lane & 15;
  const int srow = m0 + (lane >> 4) * 4;
  const int bb = srow / S_;
  const int s0 = srow - bb * S_;
  const float bah = ba[h];
  f32x4 mv = *(const f32x4*)&mask[(size_t)bb * S_ + s0];
  f32x4 outv;
#pragma unroll
  for (int j = 0; j < 4; ++j)
    outv[j] = (acc[j] + bah) * SCALE + mv[j];
  *(f32x4*)&scores[((size_t)(bb * H_ + h)) * S_ + s0] = outv;
}

// ---------------------------------------------------------------------------
// softmax over each scores row -> normalized weights
// ---------------------------------------------------------------------------
__global__ __launch_bounds__(256)
void softmax_rows(const float* __restrict__ scores, float* __restrict__ wout) {
  __shared__ float rA[4], rB[4];
  const int tid = threadIdx.x, lane = tid & 63, wid = tid >> 6;
  const float* srow = scores + (size_t)blockIdx.x * S_;
  float* wrow = wout + (size_t)blockIdx.x * S_;
  f32x4 v0 = *(const f32x4*)&srow[tid * 4];
  f32x4 v1 = *(const f32x4*)&srow[1024 + tid * 4];
  float mx = fmaxf(fmaxf(fmaxf(v0[0], v0[1]), fmaxf(v0[2], v0[3])),
                   fmaxf(fmaxf(v1[0], v1[1]), fmaxf(v1[2], v1[3])));
#pragma unroll
  for (int o = 32; o; o >>= 1) mx = fmaxf(mx, __shfl_xor(mx, o));
  if (lane == 0) rA[wid] = mx;
  __syncthreads();
  mx = fmaxf(fmaxf(rA[0], rA[1]), fmaxf(rA[2], rA[3]));
  float sum = 0.f;
#pragma unroll
  for (int i = 0; i < 4; ++i) { v0[i] = __expf(v0[i] - mx); sum += v0[i]; }
#pragma unroll
  for (int i = 0; i < 4; ++i) { v1[i] = __expf(v1[i] - mx); sum += v1[i]; }
#pragma unroll
  for (int o = 32; o; o >>= 1) sum += __shfl_xor(sum, o);
  if (lane == 0) rB[wid] = sum;
  __syncthreads();
  sum = rB[0] + rB[1] + rB[2] + rB[3];
  const float inv = 1.0f / sum;
#pragma unroll
  for (int i = 0; i < 4; ++i) { v0[i] *= inv; v1[i] *= inv; }
  *(f32x4*)&wrow[tid * 4] = v0;
  *(f32x4*)&wrow[1024 + tid * 4] = v1;
}

// ---------------------------------------------------------------------------
// pool partials over 32-row chunks (coalesced bf16x8)
// ---------------------------------------------------------------------------
__global__ __launch_bounds__(256)
void pool_partial(const bf16_t* __restrict__ X, const float* __restrict__ w,
                  float* __restrict__ partials) {
  __shared__ float sm[2][1024];
  const int tid = threadIdx.x;
  const int chunk = blockIdx.x, b = blockIdx.y;
  const int s0 = chunk * 32;
  const int dc = (tid & 127) * 8;
  const int sp = tid >> 7;
  const int h = dc >> 6;
  const float* wrow = w + ((size_t)b * H_ + h) * S_ + s0;
  const bf16_t* Xb = X + ((size_t)b * S_ + s0) * D_ + dc;
  float acc[8] = {};
  for (int s = sp; s < 32; s += 2) {
    bf16x8 xv = *(const bf16x8*)&Xb[(size_t)s * D_];
    float wt = wrow[s];
#pragma unroll
    for (int j = 0; j < 8; ++j) acc[j] += wt * (float)xv[j];
  }
#pragma unroll
  for (int j = 0; j < 8; ++j) sm[sp][dc + j] = acc[j];
  __syncthreads();
  const int d0 = tid * 4;
  f32x4 r;
#pragma unroll
  for (int j = 0; j < 4; ++j) r[j] = sm[0][d0 + j] + sm[1][d0 + j];
  *(f32x4*)&partials[((size_t)chunk * B_ + b) * D_ + d0] = r;
}

__global__ __launch_bounds__(256)
void pool_reduce(const float* __restrict__ partials, float* __restrict__ pooled) {
  const int idx = blockIdx.x * 256 + threadIdx.x;
  float s = 0.f;
#pragma unroll 8
  for (int c = 0; c < 64; ++c) s += partials[(size_t)c * (B_ * D_) + idx];
  pooled[idx] = s;
}

// ---------------------------------------------------------------------------
extern "C" void kernel_launch(void* const* d_in, const int* in_sizes, int n_in,
                              void* d_out, int out_size, void* d_ws, size_t ws_size,
                              hipStream_t stream) {
  const float* hs   = (const float*)d_in[0];
  const float* mask = (const float*)d_in[1];
  const float* Wq   = (const float*)d_in[2];
  const float* bq   = (const float*)d_in[3];
  const float* Wqa  = (const float*)d_in[4];
  const float* bqa  = (const float*)d_in[5];
  const float* Wk   = (const float*)d_in[6];
  const float* bk   = (const float*)d_in[7];
  const float* Wka  = (const float*)d_in[8];
  const float* bka  = (const float*)d_in[9];
  const float* Wt   = (const float*)d_in[10];
  const float* bt   = (const float*)d_in[11];

  char* ws = (char*)d_ws;
  float*  pq    = (float*)(ws + (64u << 10));
  float*  pk    = (float*)(ws + (128u << 10));
  bf16_t* WqaT  = (bf16_t*)(ws + (1u << 20));
  bf16_t* WkaT  = (bf16_t*)(ws + (1u << 20) + 32768);
  bf16_t* WqT   = (bf16_t*)(ws + (2u << 20));
  bf16_t* WkT   = (bf16_t*)(ws + (4u << 20));
  bf16_t* WtT   = (bf16_t*)(ws + (6u << 20));
  bf16_t* hsb   = (bf16_t*)(ws + (8u << 20));
  bf16_t* mq    = (bf16_t*)(ws + (8u << 20) + ((size_t)64 << 20));
  bf16_t* mqk   = (bf16_t*)(ws + (8u << 20) + ((size_t)128 << 20));
  float* scores = (float*)(ws + (8u << 20) + ((size_t)192 << 20));
  float* wsm    = (float*)(ws + (8u << 20) + ((size_t)194 << 20));
  float* parts  = (float*)(ws + (8u << 20) + ((size_t)196 << 20));

  // prep
  f32_to_bf16<<<16384, 256, 0, stream>>>(hs, hsb);
  transpose1024_all<<<dim3(16, 16, 3), 256, 0, stream>>>(Wq, Wk, Wt, WqT, WkT, WtT);
  transpose_small_all<<<8, 256, 0, stream>>>(Wqa, Wka, WqaT, WkaT);

  // mixed_q = hsb @ Wq + bq
  gemm_bt<0><<<2048, 256, 0, stream>>>(hsb, WqT, bq, mq, nullptr, nullptr, nullptr);

  score_kernel<<<512, 256, 0, stream>>>(mq, WqaT, bqa, mask, scores);
  softmax_rows<<<256, 256, 0, stream>>>(scores, wsm);
  pool_partial<<<dim3(64, 16), 256, 0, stream>>>(mq, wsm, parts);
  pool_reduce<<<64, 256, 0, stream>>>(parts, pq);

  // mixed_qk = (hsb @ Wk + bk) * pooled_q
  gemm_bt<1><<<2048, 256, 0, stream>>>(hsb, WkT, bk, mqk, pq, nullptr, nullptr);

  score_kernel<<<512, 256, 0, stream>>>(mqk, WkaT, bka, mask, scores);
  softmax_rows<<<256, 256, 0, stream>>>(scores, wsm);
  pool_partial<<<dim3(64, 16), 256, 0, stream>>>(mqk, wsm, parts);
  pool_reduce<<<64, 256, 0, stream>>>(parts, pk);

  // out = (mq * pk) @ Wt + bt + mixed_q   (weighted fused into A-staging)
  gemm_bt<2><<<2048, 256, 0, stream>>>(mq, WtT, bt, d_out, nullptr, mq, pk);
}